// Round 3
// baseline (14.840 us; speedup 1.0000x reference)
//
#include <hip/hip_runtime.h>

#define D_DIM 32768
#define NT 64
#define NKEYS 120
#define TPB 1024
#define DB 128      // dims per block
#define NW 16       // waves per block

__constant__ int c_feat_idx[NKEYS] = {
    557, 581, 553, 551, 92, 554, 579, 570, 573, 577,
    565, 286, 555, 549, 13, 550, 63, 580, 556, 564,
    0, 576, 567, 552, 578, 588, 597, 566, 571, 44,
    572, 574, 14, 582, 381, 594, 4, 593, 218, 25,
    84, 592, 3, 591, 547, 561, 562, 548, 319, 596,
    558, 563, 87, 65, 599, 17, 88, 2, 49, 309,
    6, 81, 15, 590, 589, 43, 273, 420, 546, 568,
    400, 277, 202, 287, 434, 435, 423, 431, 301, 417,
    412, 205, 179, 327, 176, 442, 172, 450, 391, 163,
    154, 480, 485, 490, 491, 498, 503, 507, 509, 452,
    239, 388, 219, 303, 292, 310, 316, 320, 322, 324,
    326, 330, 336, 263, 262, 339, 340, 256, 345, 347};

__device__ __forceinline__ int level_idx(float x) {
    // replicate: clip(x,-5,5); round(((x+5)/10)*2047) half-to-even; clip 0..2047
    x = fminf(fmaxf(x, -5.0f), 5.0f);
    float v = (x + 5.0f) / 10.0f * 2047.0f;
    int i = (int)rintf(v);
    return min(max(i, 0), 2047);
}

__global__ __launch_bounds__(TPB) void hdc_encode_kernel(
    const float* __restrict__ input,
    const float* __restrict__ feat,
    const float* __restrict__ Wx,
    const float* __restrict__ Wy,
    const float* __restrict__ Wz,
    const float* __restrict__ Wt,
    const float* __restrict__ keys,
    float* __restrict__ out)
{
    __shared__ int   s_meta[NW][DB];
    __shared__ float s_f[NW][DB];

    const int tid  = threadIdx.x;
    const int wave = __builtin_amdgcn_readfirstlane(tid >> 6);  // 0..15
    const int lane = tid & 63;
    const int d0 = blockIdx.x * DB + lane * 2;   // this lane's two dims

    // ---- per-wave uniform index computation (scalar loads, no LDS/barrier) ----
    int rowx[4], rowy[4], rowz[4], rowt[4];
#pragma unroll
    for (int k = 0; k < 4; ++k) {
        int t = wave * 4 + k;                    // wave-uniform
        float x = input[t * 4 + 1];
        float y = input[t * 4 + 2];
        float z = input[t * 4 + 3];
        rowx[k] = __builtin_amdgcn_readfirstlane(level_idx(x));
        rowy[k] = __builtin_amdgcn_readfirstlane(level_idx(y));
        rowz[k] = __builtin_amdgcn_readfirstlane(level_idx(z));
        float tv = (float)t;
        int it = (int)rintf(tv / 64.0f * 63.0f);
        rowt[k] = __builtin_amdgcn_readfirstlane(min(max(it, 0), NT - 1));
    }

    const int nk = (wave < 8) ? 8 : 7;           // keys per wave (8*8 + 8*7 = 120)
    const int j0 = (wave < 8) ? wave * 8 : 64 + (wave - 8) * 7;
    int fxv[8];
#pragma unroll
    for (int k = 0; k < 8; ++k) {
        if (k < nk) {
            float fv = feat[c_feat_idx[j0 + k]];
            fv = fminf(fmaxf(fv, -1.0f), 1.0f);
            fxv[k] = __builtin_amdgcn_readfirstlane((int)rintf((fv + 1.0f) * 0.5f * 32768.0f));
        } else {
            fxv[k] = 0;
        }
    }

    // ---- stage ALL gather loads into registers, issued back-to-back ----
    float2 sx[4], sy[4], sz[4], st[4];
#pragma unroll
    for (int k = 0; k < 4; ++k) {
        sx[k] = *(const float2*)(Wx + ((size_t)rowx[k] << 15) + d0);
        sy[k] = *(const float2*)(Wy + ((size_t)rowy[k] << 15) + d0);
        sz[k] = *(const float2*)(Wz + ((size_t)rowz[k] << 15) + d0);
        st[k] = *(const float2*)(Wt + ((size_t)rowt[k] << 15) + d0);
    }
    float2 kv[8];
#pragma unroll
    for (int k = 0; k < 8; ++k) {
        if (k < nk)
            kv[k] = *(const float2*)(keys + ((size_t)(j0 + k) << 15) + d0);
    }

    // ---- consume: sample sign-parity + any3 ----
    unsigned sg0 = 0u, sg1 = 0u;
    int a30 = 0, a31 = 0;
#pragma unroll
    for (int k = 0; k < 4; ++k) {
        float sA = sx[k].x + sy[k].x + sz[k].x;  // in {±1, ±3} exactly
        float sB = sx[k].y + sy[k].y + sz[k].y;
        sg0 ^= __float_as_uint(sA * st[k].x);
        sg1 ^= __float_as_uint(sB * st[k].y);
        a30 |= (fabsf(sA) > 2.0f) ? 1 : 0;
        a31 |= (fabsf(sB) > 2.0f) ? 1 : 0;
    }

    // ---- consume: thermometer-keyed feature sum ----
    float f0 = 0.0f, f1 = 0.0f;
#pragma unroll
    for (int k = 0; k < 8; ++k) {
        if (k < nk) {
            int fx = fxv[k];
            f0 += (d0 < fx)     ? kv[k].x : -kv[k].x;
            f1 += (d0 + 1 < fx) ? kv[k].y : -kv[k].y;
        }
    }

    const int col = lane * 2;
    s_meta[wave][col]     = (int)(sg0 >> 31) | (a30 << 8);
    s_meta[wave][col + 1] = (int)(sg1 >> 31) | (a31 << 8);
    s_f[wave][col]     = f0;
    s_f[wave][col + 1] = f1;
    __syncthreads();

    if (tid < DB) {
        int msum = 0;
        float f = 0.0f;
#pragma unroll
        for (int w2 = 0; w2 < NW; ++w2) {
            msum += s_meta[w2][tid];
            f    += s_f[w2][tid];
        }
        bool neg  = (msum & 1) != 0;          // parity of sign bits = sign of product
        bool any3 = (msum & 0xFF00) != 0;     // any |x+y+z| == 3
        float o;
        if (f >= 0.0f) o = neg ? -1.0f : 1.0f;
        else           o = (neg && any3) ? 1.0f : -1.0f;
        out[blockIdx.x * DB + tid] = o;
    }
}

extern "C" void kernel_launch(void* const* d_in, const int* in_sizes, int n_in,
                              void* d_out, int out_size, void* d_ws, size_t ws_size,
                              hipStream_t stream) {
    const float* input = (const float*)d_in[0];
    const float* feat  = (const float*)d_in[1];
    const float* Wx    = (const float*)d_in[2];
    const float* Wy    = (const float*)d_in[3];
    const float* Wz    = (const float*)d_in[4];
    const float* Wt    = (const float*)d_in[5];
    const float* keys  = (const float*)d_in[6];
    float* out = (float*)d_out;

    dim3 grid(D_DIM / DB);   // 256 blocks -> one per CU
    dim3 block(TPB);
    hipLaunchKernelGGL(hdc_encode_kernel, grid, block, 0, stream,
                       input, feat, Wx, Wy, Wz, Wt, keys, out);
}